// Round 1
// baseline (8882.427 us; speedup 1.0000x reference)
//
#include <hip/hip_runtime.h>
#include <hip/hip_bf16.h>
#include <math.h>

// Problem constants (B=8, S=2048, D=1024, DK=DV=128, FF=4096)
#define M_TOT   16384   // B*S rows
#define D_MODEL 1024
#define D_HEAD  128
#define SEQ     2048
#define NBATCH  8
#define D_FF    4096

// ---------------- helpers ----------------
__device__ __forceinline__ float4 load4f(const float* p) { return *(const float4*)p; }
__device__ __forceinline__ float4 load4f(const __hip_bfloat16* p) {
  ushort4 u = *(const ushort4*)p;
  float4 r;
  r.x = __uint_as_float((unsigned)u.x << 16);
  r.y = __uint_as_float((unsigned)u.y << 16);
  r.z = __uint_as_float((unsigned)u.z << 16);
  r.w = __uint_as_float((unsigned)u.w << 16);
  return r;
}
__device__ __forceinline__ void store1(float* p, float v) { *p = v; }
__device__ __forceinline__ void store1(__hip_bfloat16* p, float v) { *p = __float2bfloat16(v); }

// ---------------- LayerNorm: one block (256 thr) per row of 1024 ----------------
__global__ __launch_bounds__(256) void ln_kernel(const float* __restrict__ in,
                                                 const float* __restrict__ gamma,
                                                 const float* __restrict__ beta,
                                                 float* __restrict__ out) {
  __shared__ float shs[4], shq[4];
  const int row = blockIdx.x;
  const int t = threadIdx.x;
  const float4* inr = (const float4*)(in + (size_t)row * D_MODEL);
  float4 v = inr[t];                       // 256 threads * float4 = 1024 floats
  float s = v.x + v.y + v.z + v.w;
  float q = v.x * v.x + v.y * v.y + v.z * v.z + v.w * v.w;
#pragma unroll
  for (int o = 32; o > 0; o >>= 1) {
    s += __shfl_down(s, o, 64);
    q += __shfl_down(q, o, 64);
  }
  const int lane = t & 63, w = t >> 6;
  if (lane == 0) { shs[w] = s; shq[w] = q; }
  __syncthreads();
  if (t == 0) {
    shs[0] = shs[0] + shs[1] + shs[2] + shs[3];
    shq[0] = shq[0] + shq[1] + shq[2] + shq[3];
  }
  __syncthreads();
  const float mu = shs[0] * (1.0f / D_MODEL);
  const float var = shq[0] * (1.0f / D_MODEL) - mu * mu;
  const float rs = rsqrtf(var + 1e-5f);
  float4 gv = ((const float4*)gamma)[t];
  float4 bv = ((const float4*)beta)[t];
  float4 o;
  o.x = (v.x - mu) * rs * gv.x + bv.x;
  o.y = (v.y - mu) * rs * gv.y + bv.y;
  o.z = (v.z - mu) * rs * gv.z + bv.z;
  o.w = (v.w - mu) * rs * gv.w + bv.w;
  ((float4*)(out + (size_t)row * D_MODEL))[t] = o;
}

// ---------------- Tiled GEMM: C[M,N] = act(A[M,K] @ B[K,N] + bias) (+ res) ----------------
// 64x64 block tile, BK=16, 256 threads, 4x4 register blocking. fp32 accumulate.
// All dims are multiples of tile sizes in this problem -> no bounds checks.
template <typename TA, typename TC, bool GELU, bool RES>
__global__ __launch_bounds__(256) void gemm_kernel(const TA* __restrict__ A,
                                                   const float* __restrict__ B,
                                                   const float* __restrict__ bias,
                                                   const float* __restrict__ res,
                                                   TC* __restrict__ C,
                                                   int M, int N, int K) {
  __shared__ float As[16][68];   // [kk][m], padded row (68*4B) -> conflict-free & 16B aligned
  __shared__ float Bs[16][64];   // [kk][n]
  const int tid = threadIdx.x;
  const int tx = tid & 15, ty = tid >> 4;
  const int row0 = blockIdx.y << 6, col0 = blockIdx.x << 6;
  const int am = tid >> 2, ak = (tid & 3) << 2;   // A tile: 64 rows x 16 k, float4 per thread
  const int bk = tid >> 4, bn = (tid & 15) << 2;  // B tile: 16 k x 64 cols, float4 per thread
  const TA* Ap = A + (size_t)(row0 + am) * K + ak;
  const float* Bp = B + (size_t)bk * N + col0 + bn;
  float acc[4][4] = {};
  for (int k0 = 0; k0 < K; k0 += 16) {
    float4 a4 = load4f(Ap); Ap += 16;
    float4 b4 = *(const float4*)Bp; Bp += (size_t)16 * N;
    As[ak + 0][am] = a4.x;
    As[ak + 1][am] = a4.y;
    As[ak + 2][am] = a4.z;
    As[ak + 3][am] = a4.w;
    *(float4*)&Bs[bk][bn] = b4;
    __syncthreads();
#pragma unroll
    for (int kk = 0; kk < 16; kk++) {
      float4 a = *(const float4*)&As[kk][ty << 2];
      float4 b = *(const float4*)&Bs[kk][tx << 2];
      float ar[4] = {a.x, a.y, a.z, a.w};
      float br[4] = {b.x, b.y, b.z, b.w};
#pragma unroll
      for (int i = 0; i < 4; i++)
#pragma unroll
        for (int j = 0; j < 4; j++)
          acc[i][j] = fmaf(ar[i], br[j], acc[i][j]);
    }
    __syncthreads();
  }
#pragma unroll
  for (int i = 0; i < 4; i++) {
    const int row = row0 + (ty << 2) + i;
#pragma unroll
    for (int j = 0; j < 4; j++) {
      const int col = col0 + (tx << 2) + j;
      float v = acc[i][j] + bias[col];
      if (GELU) v = 0.5f * v * (1.0f + erff(v * 0.70710678118654752f));
      if (RES) v += res[(size_t)row * N + col];
      store1(C + (size_t)row * N + col, v);
    }
  }
}

// ---------------- Attention: one block (256 thr) per (batch, query row) ----------------
// Scores for all 2048 keys live in LDS (8 KB); softmax in-block; H = P @ V.
__global__ __launch_bounds__(256) void attn_kernel(const float* __restrict__ q,
                                                   const float* __restrict__ k,
                                                   const float* __restrict__ v,
                                                   float* __restrict__ H) {
  __shared__ float qs[D_HEAD];
  __shared__ float s[SEQ];
  __shared__ float sh1[4], sh2[4];
  __shared__ float hacc[256];
  const int b = blockIdx.y, qi = blockIdx.x, t = threadIdx.x;
  const float* qrow = q + ((size_t)b * SEQ + qi) * D_HEAD;
  const float* kb = k + (size_t)b * SEQ * D_HEAD;
  const float* vb = v + (size_t)b * SEQ * D_HEAD;
  if (t < D_HEAD / 4) ((float4*)qs)[t] = ((const float4*)qrow)[t];
  __syncthreads();

  const float scale = 0.08838834764831845f;  // 1/sqrt(128)
  float lmax = -3.0e38f;
  for (int kk = t; kk < SEQ; kk += 256) {
    const float4* kr = (const float4*)(kb + (size_t)kk * D_HEAD);
    float acc = 0.f;
#pragma unroll
    for (int d = 0; d < D_HEAD / 4; d++) {
      float4 kv = kr[d];
      float4 qv = ((float4*)qs)[d];
      acc += kv.x * qv.x + kv.y * qv.y + kv.z * qv.z + kv.w * qv.w;
    }
    acc *= scale;
    s[kk] = acc;
    lmax = fmaxf(lmax, acc);
  }
#pragma unroll
  for (int o = 32; o > 0; o >>= 1) lmax = fmaxf(lmax, __shfl_down(lmax, o, 64));
  const int lane = t & 63, w = t >> 6;
  if (lane == 0) sh1[w] = lmax;
  __syncthreads();
  if (t == 0) sh1[0] = fmaxf(fmaxf(sh1[0], sh1[1]), fmaxf(sh1[2], sh1[3]));
  __syncthreads();
  const float gmax = sh1[0];

  float lsum = 0.f;
  for (int kk = t; kk < SEQ; kk += 256) {
    float p = __expf(s[kk] - gmax);
    s[kk] = p;
    lsum += p;
  }
#pragma unroll
  for (int o = 32; o > 0; o >>= 1) lsum += __shfl_down(lsum, o, 64);
  if (lane == 0) sh2[w] = lsum;
  __syncthreads();
  if (t == 0) sh2[0] = sh2[0] + sh2[1] + sh2[2] + sh2[3];
  __syncthreads();
  const float inv = 1.0f / sh2[0];

  // H[d] = sum_k p[k] * V[k][d]; 256 threads = 128 dims x 2 halves of k
  const int d = t & 127, half = t >> 7;
  float acc = 0.f;
  for (int kk = half; kk < SEQ; kk += 2)
    acc += s[kk] * vb[(size_t)kk * D_HEAD + d];
  hacc[t] = acc;
  __syncthreads();
  if (t < 128)
    H[((size_t)b * SEQ + qi) * D_HEAD + t] = (hacc[t] + hacc[t + 128]) * inv;
}

// ---------------- launch ----------------
extern "C" void kernel_launch(void* const* d_in, const int* in_sizes, int n_in,
                              void* d_out, int out_size, void* d_ws, size_t ws_size,
                              hipStream_t stream) {
  const float* x     = (const float*)d_in[0];
  const float* ln1_g = (const float*)d_in[1];
  const float* ln1_b = (const float*)d_in[2];
  const float* Wq    = (const float*)d_in[3];
  const float* bq    = (const float*)d_in[4];
  const float* Wk    = (const float*)d_in[5];
  const float* bkp   = (const float*)d_in[6];
  const float* Wv    = (const float*)d_in[7];
  const float* bvp   = (const float*)d_in[8];
  const float* Wo    = (const float*)d_in[9];
  const float* bo    = (const float*)d_in[10];
  const float* ln2_g = (const float*)d_in[11];
  const float* ln2_b = (const float*)d_in[12];
  const float* W1    = (const float*)d_in[13];
  const float* b1    = (const float*)d_in[14];
  const float* W2    = (const float*)d_in[15];
  const float* b2    = (const float*)d_in[16];
  float* out = (float*)d_out;

  // Workspace layout (192 MiB total), with lifetime-based overlap:
  //   [0,   64M)  hbuf (ln2 out)            -- live K5..K7
  //   [64, 128M)  xn (ln1 out)              -- live K1..K4
  //   [128,136M)  q; [136,144M) k; [144,152M) v  -- live K2..K3
  //   [152,160M)  H                          -- live K3..K4
  //   [64, 192M)  act (bf16, 128 MiB)        -- live K6..K7 (overwrites dead xn/q/k/v/H)
  char* ws = (char*)d_ws;
  float* hbuf = (float*)ws;
  float* xn   = (float*)(ws + (size_t)64  * 1024 * 1024);
  float* qb   = (float*)(ws + (size_t)128 * 1024 * 1024);
  float* kbuf = (float*)(ws + (size_t)136 * 1024 * 1024);
  float* vbuf = (float*)(ws + (size_t)144 * 1024 * 1024);
  float* Hb   = (float*)(ws + (size_t)152 * 1024 * 1024);
  __hip_bfloat16* act = (__hip_bfloat16*)(ws + (size_t)64 * 1024 * 1024);

  // K1: xn = LN1(x)
  ln_kernel<<<dim3(M_TOT), dim3(256), 0, stream>>>(x, ln1_g, ln1_b, xn);
  // K2: q,k,v = xn @ W{q,k,v} + b
  gemm_kernel<float, float, false, false><<<dim3(D_HEAD / 64, M_TOT / 64), dim3(256), 0, stream>>>(
      xn, Wq, bq, nullptr, qb, M_TOT, D_HEAD, D_MODEL);
  gemm_kernel<float, float, false, false><<<dim3(D_HEAD / 64, M_TOT / 64), dim3(256), 0, stream>>>(
      xn, Wk, bkp, nullptr, kbuf, M_TOT, D_HEAD, D_MODEL);
  gemm_kernel<float, float, false, false><<<dim3(D_HEAD / 64, M_TOT / 64), dim3(256), 0, stream>>>(
      xn, Wv, bvp, nullptr, vbuf, M_TOT, D_HEAD, D_MODEL);
  // K3: H = softmax(q k^T / sqrt(dk)) v
  attn_kernel<<<dim3(SEQ, NBATCH), dim3(256), 0, stream>>>(qb, kbuf, vbuf, Hb);
  // K4: y = xn + H @ Wo + bo   -> d_out
  gemm_kernel<float, float, false, true><<<dim3(D_MODEL / 64, M_TOT / 64), dim3(256), 0, stream>>>(
      Hb, Wo, bo, xn, out, M_TOT, D_MODEL, D_HEAD);
  // K5: hbuf = LN2(y)
  ln_kernel<<<dim3(M_TOT), dim3(256), 0, stream>>>(out, ln2_g, ln2_b, hbuf);
  // K6: act = gelu(hbuf @ W1 + b1)  (bf16 store)
  gemm_kernel<float, __hip_bfloat16, true, false><<<dim3(D_FF / 64, M_TOT / 64), dim3(256), 0, stream>>>(
      hbuf, W1, b1, nullptr, act, M_TOT, D_FF, D_MODEL);
  // K7: out = y + act @ W2 + b2
  gemm_kernel<__hip_bfloat16, float, false, true><<<dim3(D_MODEL / 64, M_TOT / 64), dim3(256), 0, stream>>>(
      act, W2, b2, out, out, M_TOT, D_MODEL, D_FF);

  (void)in_sizes; (void)n_in; (void)out_size; (void)ws_size;
}

// Round 2
// 1190.810 us; speedup vs baseline: 7.4591x; 7.4591x over previous
//
#include <hip/hip_runtime.h>
#include <math.h>

// Problem constants (B=8, S=2048, D=1024, DK=DV=128, FF=4096)
#define M_TOT   16384
#define D_MODEL 1024
#define D_HEAD  128
#define SEQ     2048
#define NBATCH  8
#define D_FF    4096

typedef _Float16 f16x8 __attribute__((ext_vector_type(8)));
typedef _Float16 f16x4 __attribute__((ext_vector_type(4)));
typedef float    f32x4 __attribute__((ext_vector_type(4)));

__device__ __forceinline__ void store1(float* p, float v) { *p = v; }
__device__ __forceinline__ void store1(_Float16* p, float v) { *p = (_Float16)v; }

// ---------------- weight convert + transpose: out[n][k] = f16(in[k][n]) ----------------
__global__ __launch_bounds__(256) void convt_kernel(const float* __restrict__ in,
                                                    _Float16* __restrict__ out,
                                                    int K, int N) {
  __shared__ float t[32][33];
  const int n0 = blockIdx.x * 32, k0 = blockIdx.y * 32;
  const int tx = threadIdx.x & 31, ty = threadIdx.x >> 5;   // 32 x 8
#pragma unroll
  for (int r = 0; r < 4; r++)
    t[ty + 8 * r][tx] = in[(size_t)(k0 + ty + 8 * r) * N + n0 + tx];
  __syncthreads();
#pragma unroll
  for (int r = 0; r < 4; r++)
    out[(size_t)(n0 + ty + 8 * r) * K + k0 + tx] = (_Float16)t[tx][ty + 8 * r];
}

// ---------------- LayerNorm: one block (256 thr) per row of 1024; fp32 + f16 outs ----------------
template <bool WF32>
__global__ __launch_bounds__(256) void ln_kernel(const float* __restrict__ in,
                                                 const float* __restrict__ gamma,
                                                 const float* __restrict__ beta,
                                                 float* __restrict__ of,
                                                 _Float16* __restrict__ oh) {
  __shared__ float shs[4], shq[4];
  const int row = blockIdx.x;
  const int t = threadIdx.x;
  float4 v = ((const float4*)(in + (size_t)row * D_MODEL))[t];
  float s = v.x + v.y + v.z + v.w;
  float q = v.x * v.x + v.y * v.y + v.z * v.z + v.w * v.w;
#pragma unroll
  for (int o = 32; o > 0; o >>= 1) {
    s += __shfl_down(s, o, 64);
    q += __shfl_down(q, o, 64);
  }
  const int lane = t & 63, w = t >> 6;
  if (lane == 0) { shs[w] = s; shq[w] = q; }
  __syncthreads();
  if (t == 0) {
    shs[0] = shs[0] + shs[1] + shs[2] + shs[3];
    shq[0] = shq[0] + shq[1] + shq[2] + shq[3];
  }
  __syncthreads();
  const float mu = shs[0] * (1.0f / D_MODEL);
  const float var = shq[0] * (1.0f / D_MODEL) - mu * mu;
  const float rs = rsqrtf(var + 1e-5f);
  float4 gv = ((const float4*)gamma)[t];
  float4 bv = ((const float4*)beta)[t];
  float4 o;
  o.x = (v.x - mu) * rs * gv.x + bv.x;
  o.y = (v.y - mu) * rs * gv.y + bv.y;
  o.z = (v.z - mu) * rs * gv.z + bv.z;
  o.w = (v.w - mu) * rs * gv.w + bv.w;
  if (WF32) ((float4*)(of + (size_t)row * D_MODEL))[t] = o;
  f16x4 h4 = {(_Float16)o.x, (_Float16)o.y, (_Float16)o.z, (_Float16)o.w};
  ((f16x4*)(oh + (size_t)row * D_MODEL))[t] = h4;
}

// ---------------- MFMA GEMM: C[M,N] = act(A[M,K] @ B[K,N] + bias) (+res) ----------------
// A f16 [M][K], BT f16 [N][K] (pre-transposed). 128x128 tile, BK=32, 4 waves,
// each wave a 64x64 sub-tile = 4x4 grid of 16x16x32 MFMAs. fp32 accumulate.
template <typename TC, bool GELU, bool RES>
__global__ __launch_bounds__(256) void mfma_gemm(const _Float16* __restrict__ A,
                                                 const _Float16* __restrict__ BT,
                                                 const float* __restrict__ bias,
                                                 const float* __restrict__ res,
                                                 TC* __restrict__ C,
                                                 int M, int N, int K) {
  __shared__ _Float16 As[128 * 32];
  __shared__ _Float16 Bs[128 * 32];
  const int tid = threadIdx.x;
  const int lane = tid & 63, wid = tid >> 6;
  const int wr = wid >> 1, wc = wid & 1;
  const int row0 = blockIdx.y << 7, col0 = blockIdx.x << 7;
  const int l15 = lane & 15, quad = lane >> 4;
  const f32x4 zero = {0.f, 0.f, 0.f, 0.f};
  f32x4 acc[4][4];
#pragma unroll
  for (int i = 0; i < 4; i++)
#pragma unroll
    for (int j = 0; j < 4; j++) acc[i][j] = zero;

  const _Float16* Ag = A + (size_t)row0 * K;
  const _Float16* Bg = BT + (size_t)col0 * K;
  for (int k0 = 0; k0 < K; k0 += 32) {
#pragma unroll
    for (int p = 0; p < 2; p++) {
      const int c = tid + p * 256;          // 0..511
      const int r = c >> 2, kc = (c & 3) << 3;
      *(uint4*)&As[r * 32 + kc] = *(const uint4*)(Ag + (size_t)r * K + k0 + kc);
      *(uint4*)&Bs[r * 32 + kc] = *(const uint4*)(Bg + (size_t)r * K + k0 + kc);
    }
    __syncthreads();
    f16x8 af[4], bfr[4];
#pragma unroll
    for (int i = 0; i < 4; i++) {
      af[i]  = *(const f16x8*)&As[(wr * 64 + i * 16 + l15) * 32 + quad * 8];
      bfr[i] = *(const f16x8*)&Bs[(wc * 64 + i * 16 + l15) * 32 + quad * 8];
    }
#pragma unroll
    for (int i = 0; i < 4; i++)
#pragma unroll
      for (int j = 0; j < 4; j++)
        acc[i][j] = __builtin_amdgcn_mfma_f32_16x16x32_f16(af[i], bfr[j], acc[i][j], 0, 0, 0);
    __syncthreads();
  }
  // Epilogue. C/D layout: col = lane&15, row = quad*4 + reg  [HW-verified m89/m91]
#pragma unroll
  for (int j = 0; j < 4; j++) {
    const int col = col0 + wc * 64 + j * 16 + l15;
    const float bv = bias[col];
#pragma unroll
    for (int i = 0; i < 4; i++) {
#pragma unroll
      for (int r = 0; r < 4; r++) {
        const int row = row0 + wr * 64 + i * 16 + quad * 4 + r;
        float v = acc[i][j][r] + bv;
        if (GELU) v = 0.5f * v * (1.0f + erff(v * 0.70710678118654752f));
        if (RES) v += res[(size_t)row * N + col];
        store1(&C[(size_t)row * N + col], v);
      }
    }
  }
}

// ---------------- Flash attention: 64-query x 32-key tiles, online softmax ----------------
// Grid (SEQ/64, B), 256 threads as 16x16. Q tile + shared K/V buffer in LDS (~60 KB).
__global__ __launch_bounds__(256) void flash_attn(const float* __restrict__ q,
                                                  const float* __restrict__ k,
                                                  const float* __restrict__ v,
                                                  _Float16* __restrict__ H) {
  __shared__ float Qs[64][132];
  __shared__ float KV[32][132];
  __shared__ float Ps[64][36];
  __shared__ float mS[64], lS[64];
  const int b = blockIdx.y, q0 = blockIdx.x * 64, tid = threadIdx.x;
  const int tx = tid & 15, ty = tid >> 4;
  const float* qb = q + ((size_t)b * SEQ + q0) * D_HEAD;
  const float* kb = k + (size_t)b * SEQ * D_HEAD;
  const float* vb = v + (size_t)b * SEQ * D_HEAD;
  // stage Q (64x128 = 2048 float4)
#pragma unroll
  for (int p = 0; p < 8; p++) {
    const int idx = tid + p * 256;
    const int r = idx >> 5, c4 = idx & 31;
    *(float4*)&Qs[r][4 * c4] = *(const float4*)(qb + (size_t)r * D_HEAD + 4 * c4);
  }
  if (tid < 64) { mS[tid] = -3.0e38f; lS[tid] = 0.f; }
  float O[4][8] = {};
  const float scale = 0.08838834764831845f;  // 1/sqrt(128)

  for (int kt = 0; kt < SEQ / 32; kt++) {
    __syncthreads();
    // stage K tile (32x128 = 1024 float4)
    const float* kp = kb + (size_t)kt * 32 * D_HEAD;
#pragma unroll
    for (int p = 0; p < 4; p++) {
      const int idx = tid + p * 256;
      const int r = idx >> 5, c4 = idx & 31;
      *(float4*)&KV[r][4 * c4] = *(const float4*)(kp + (size_t)r * D_HEAD + 4 * c4);
    }
    __syncthreads();
    // S[4ty+i][2tx+j] = Q . K
    float s[4][2] = {};
    for (int d4 = 0; d4 < 32; d4++) {
      float4 qv[4], kv[2];
#pragma unroll
      for (int i = 0; i < 4; i++) qv[i] = *(const float4*)&Qs[4 * ty + i][4 * d4];
#pragma unroll
      for (int j = 0; j < 2; j++) kv[j] = *(const float4*)&KV[2 * tx + j][4 * d4];
#pragma unroll
      for (int i = 0; i < 4; i++)
#pragma unroll
        for (int j = 0; j < 2; j++)
          s[i][j] += qv[i].x * kv[j].x + qv[i].y * kv[j].y + qv[i].z * kv[j].z + qv[i].w * kv[j].w;
    }
    float rmax[4], newm[4], alpha[4], rsum[4];
#pragma unroll
    for (int i = 0; i < 4; i++) {
      s[i][0] *= scale; s[i][1] *= scale;
      rmax[i] = fmaxf(s[i][0], s[i][1]);
    }
#pragma unroll
    for (int o = 1; o < 16; o <<= 1)
#pragma unroll
      for (int i = 0; i < 4; i++) rmax[i] = fmaxf(rmax[i], __shfl_xor(rmax[i], o, 64));
#pragma unroll
    for (int i = 0; i < 4; i++) {
      const float om = mS[4 * ty + i];
      const float nm = fmaxf(om, rmax[i]);
      newm[i] = nm;
      alpha[i] = __expf(om - nm);
      s[i][0] = __expf(s[i][0] - nm);
      s[i][1] = __expf(s[i][1] - nm);
      rsum[i] = s[i][0] + s[i][1];
    }
#pragma unroll
    for (int o = 1; o < 16; o <<= 1)
#pragma unroll
      for (int i = 0; i < 4; i++) rsum[i] += __shfl_xor(rsum[i], o, 64);
#pragma unroll
    for (int i = 0; i < 4; i++) {
      *(float2*)&Ps[4 * ty + i][2 * tx] = make_float2(s[i][0], s[i][1]);
#pragma unroll
      for (int j = 0; j < 8; j++) O[i][j] *= alpha[i];
    }
    __syncthreads();   // Ps written; K reads done
    if (tx == 0) {
#pragma unroll
      for (int i = 0; i < 4; i++) {
        mS[4 * ty + i] = newm[i];
        lS[4 * ty + i] = lS[4 * ty + i] * alpha[i] + rsum[i];
      }
    }
    // stage V tile into the same buffer
    const float* vp = vb + (size_t)kt * 32 * D_HEAD;
#pragma unroll
    for (int p = 0; p < 4; p++) {
      const int idx = tid + p * 256;
      const int r = idx >> 5, c4 = idx & 31;
      *(float4*)&KV[r][4 * c4] = *(const float4*)(vp + (size_t)r * D_HEAD + 4 * c4);
    }
    __syncthreads();
    // O[4ty+i][8tx+c] += sum_k Ps[4ty+i][k] * V[k][8tx+c]
#pragma unroll 2
    for (int kk4 = 0; kk4 < 8; kk4++) {
      float4 p4[4];
#pragma unroll
      for (int i = 0; i < 4; i++) p4[i] = *(const float4*)&Ps[4 * ty + i][4 * kk4];
#pragma unroll
      for (int c = 0; c < 4; c++) {
        const int kk = 4 * kk4 + c;
        const float4 v0 = *(const float4*)&KV[kk][8 * tx];
        const float4 v1 = *(const float4*)&KV[kk][8 * tx + 4];
#pragma unroll
        for (int i = 0; i < 4; i++) {
          const float pv = (c == 0) ? p4[i].x : (c == 1) ? p4[i].y : (c == 2) ? p4[i].z : p4[i].w;
          O[i][0] += pv * v0.x; O[i][1] += pv * v0.y; O[i][2] += pv * v0.z; O[i][3] += pv * v0.w;
          O[i][4] += pv * v1.x; O[i][5] += pv * v1.y; O[i][6] += pv * v1.z; O[i][7] += pv * v1.w;
        }
      }
    }
  }
  __syncthreads();
#pragma unroll
  for (int i = 0; i < 4; i++) {
    const float inv = 1.0f / lS[4 * ty + i];
    _Float16* hp = H + ((size_t)b * SEQ + q0 + 4 * ty + i) * D_HEAD + 8 * tx;
#pragma unroll
    for (int j = 0; j < 8; j++) hp[j] = (_Float16)(O[i][j] * inv);
  }
}

// ---------------- launch ----------------
extern "C" void kernel_launch(void* const* d_in, const int* in_sizes, int n_in,
                              void* d_out, int out_size, void* d_ws, size_t ws_size,
                              hipStream_t stream) {
  const float* x     = (const float*)d_in[0];
  const float* ln1_g = (const float*)d_in[1];
  const float* ln1_b = (const float*)d_in[2];
  const float* Wq    = (const float*)d_in[3];
  const float* bq    = (const float*)d_in[4];
  const float* Wk    = (const float*)d_in[5];
  const float* bk    = (const float*)d_in[6];
  const float* Wv    = (const float*)d_in[7];
  const float* bv    = (const float*)d_in[8];
  const float* Wo    = (const float*)d_in[9];
  const float* bo    = (const float*)d_in[10];
  const float* ln2_g = (const float*)d_in[11];
  const float* ln2_b = (const float*)d_in[12];
  const float* W1    = (const float*)d_in[13];
  const float* b1    = (const float*)d_in[14];
  const float* W2    = (const float*)d_in[15];
  const float* b2    = (const float*)d_in[16];
  float* out = (float*)d_out;

  // Workspace layout (<=180 MiB), lifetime-overlapped:
  //  [0,20M)    f16 transposed weights (whole launch)
  //  [20,84M)   xn_f32 (K2..K5)   -- act f16 [20,148M) (K6..K7) reuses this + qkv/H
  //  [84,116M)  xn_f16 (K2..K3)
  //  [116,140M) q,k,v fp32 (K3..K4)
  //  [140,144M) H f16 (K4..K5)
  //  [148,180M) h_f16 (K6..K7)
  char* ws = (char*)d_ws;
  const size_t MB = 1024 * 1024;
  _Float16* W1T = (_Float16*)(ws + 0 * MB);          // [4096][1024]
  _Float16* W2T = (_Float16*)(ws + 8 * MB);          // [1024][4096]
  _Float16* WqT = (_Float16*)(ws + 16 * MB);         // [128][1024]
  _Float16* WkT = (_Float16*)(ws + 16 * MB + 256 * 1024);
  _Float16* WvT = (_Float16*)(ws + 16 * MB + 512 * 1024);
  _Float16* WoT = (_Float16*)(ws + 16 * MB + 768 * 1024);  // [1024][128]
  float*    xn_f32 = (float*)(ws + 20 * MB);
  _Float16* xn_f16 = (_Float16*)(ws + 84 * MB);
  float*    qb  = (float*)(ws + 116 * MB);
  float*    kbf = (float*)(ws + 124 * MB);
  float*    vbf = (float*)(ws + 132 * MB);
  _Float16* Hb  = (_Float16*)(ws + 140 * MB);
  _Float16* act = (_Float16*)(ws + 20 * MB);
  _Float16* h16 = (_Float16*)(ws + 148 * MB);

  // K0: convert+transpose weights to f16 [N][K]
  convt_kernel<<<dim3(D_FF / 32, D_MODEL / 32), 256, 0, stream>>>(W1, W1T, D_MODEL, D_FF);
  convt_kernel<<<dim3(D_MODEL / 32, D_FF / 32), 256, 0, stream>>>(W2, W2T, D_FF, D_MODEL);
  convt_kernel<<<dim3(D_HEAD / 32, D_MODEL / 32), 256, 0, stream>>>(Wq, WqT, D_MODEL, D_HEAD);
  convt_kernel<<<dim3(D_HEAD / 32, D_MODEL / 32), 256, 0, stream>>>(Wk, WkT, D_MODEL, D_HEAD);
  convt_kernel<<<dim3(D_HEAD / 32, D_MODEL / 32), 256, 0, stream>>>(Wv, WvT, D_MODEL, D_HEAD);
  convt_kernel<<<dim3(D_MODEL / 32, D_HEAD / 32), 256, 0, stream>>>(Wo, WoT, D_HEAD, D_MODEL);
  // K1: LN1 -> xn_f32 + xn_f16
  ln_kernel<true><<<dim3(M_TOT), 256, 0, stream>>>(x, ln1_g, ln1_b, xn_f32, xn_f16);
  // K2: q,k,v fp32
  mfma_gemm<float, false, false><<<dim3(1, M_TOT / 128), 256, 0, stream>>>(
      xn_f16, WqT, bq, nullptr, qb, M_TOT, D_HEAD, D_MODEL);
  mfma_gemm<float, false, false><<<dim3(1, M_TOT / 128), 256, 0, stream>>>(
      xn_f16, WkT, bk, nullptr, kbf, M_TOT, D_HEAD, D_MODEL);
  mfma_gemm<float, false, false><<<dim3(1, M_TOT / 128), 256, 0, stream>>>(
      xn_f16, WvT, bv, nullptr, vbf, M_TOT, D_HEAD, D_MODEL);
  // K3: flash attention -> H f16
  flash_attn<<<dim3(SEQ / 64, NBATCH), 256, 0, stream>>>(qb, kbf, vbf, Hb);
  // K4: y = xn + H @ Wo + bo -> out (fp32)
  mfma_gemm<float, false, true><<<dim3(D_MODEL / 128, M_TOT / 128), 256, 0, stream>>>(
      Hb, WoT, bo, xn_f32, out, M_TOT, D_MODEL, D_HEAD);
  // K5: LN2 -> h_f16
  ln_kernel<false><<<dim3(M_TOT), 256, 0, stream>>>(out, ln2_g, ln2_b, nullptr, h16);
  // K6: act = gelu(h @ W1 + b1)  f16
  mfma_gemm<_Float16, true, false><<<dim3(D_FF / 128, M_TOT / 128), 256, 0, stream>>>(
      h16, W1T, b1, nullptr, act, M_TOT, D_FF, D_MODEL);
  // K7: out = y + act @ W2 + b2
  mfma_gemm<float, false, true><<<dim3(D_MODEL / 128, M_TOT / 128), 256, 0, stream>>>(
      act, W2T, b2, out, out, M_TOT, D_MODEL, D_FF);

  (void)in_sizes; (void)n_in; (void)out_size; (void)ws_size;
}

// Round 3
// 811.679 us; speedup vs baseline: 10.9433x; 1.4671x over previous
//
#include <hip/hip_runtime.h>
#include <math.h>

// Problem constants (B=8, S=2048, D=1024, DK=DV=128, FF=4096)
#define M_TOT   16384
#define D_MODEL 1024
#define D_HEAD  128
#define SEQ     2048
#define NBATCH  8
#define D_FF    4096

typedef _Float16 f16x8 __attribute__((ext_vector_type(8)));
typedef _Float16 f16x4 __attribute__((ext_vector_type(4)));
typedef float    f32x4 __attribute__((ext_vector_type(4)));

#define ATT_SCALE 0.08838834764831845f  // 1/sqrt(128)

__device__ __forceinline__ void gload_lds16(const _Float16* g, _Float16* l) {
  __builtin_amdgcn_global_load_lds(
      (const __attribute__((address_space(1))) unsigned int*)g,
      (__attribute__((address_space(3))) unsigned int*)l, 16, 0, 0);
}
__device__ __forceinline__ unsigned short f16bits(float v) {
  union { _Float16 f; unsigned short u; } cv; cv.f = (_Float16)v; return cv.u;
}

// ---------------- weight convert + transpose: out[n][k] = f16(in[k][n]) ----------------
__global__ __launch_bounds__(256) void convt_kernel(const float* __restrict__ in,
                                                    _Float16* __restrict__ out,
                                                    int K, int N) {
  __shared__ float t[32][33];
  const int n0 = blockIdx.x * 32, k0 = blockIdx.y * 32;
  const int tx = threadIdx.x & 31, ty = threadIdx.x >> 5;   // 32 x 8
#pragma unroll
  for (int r = 0; r < 4; r++)
    t[ty + 8 * r][tx] = in[(size_t)(k0 + ty + 8 * r) * N + n0 + tx];
  __syncthreads();
#pragma unroll
  for (int r = 0; r < 4; r++)
    out[(size_t)(n0 + ty + 8 * r) * K + k0 + tx] = (_Float16)t[tx][ty + 8 * r];
}

// ---------------- LayerNorm: one block (256 thr) per row of 1024 ----------------
template <bool WF32>
__global__ __launch_bounds__(256) void ln_kernel(const float* __restrict__ in,
                                                 const float* __restrict__ gamma,
                                                 const float* __restrict__ beta,
                                                 float* __restrict__ of,
                                                 _Float16* __restrict__ oh) {
  __shared__ float shs[4], shq[4];
  const int row = blockIdx.x;
  const int t = threadIdx.x;
  float4 v = ((const float4*)(in + (size_t)row * D_MODEL))[t];
  float s = v.x + v.y + v.z + v.w;
  float q = v.x * v.x + v.y * v.y + v.z * v.z + v.w * v.w;
#pragma unroll
  for (int o = 32; o > 0; o >>= 1) {
    s += __shfl_down(s, o, 64);
    q += __shfl_down(q, o, 64);
  }
  const int lane = t & 63, w = t >> 6;
  if (lane == 0) { shs[w] = s; shq[w] = q; }
  __syncthreads();
  if (t == 0) {
    shs[0] = shs[0] + shs[1] + shs[2] + shs[3];
    shq[0] = shq[0] + shq[1] + shq[2] + shq[3];
  }
  __syncthreads();
  const float mu = shs[0] * (1.0f / D_MODEL);
  const float var = shq[0] * (1.0f / D_MODEL) - mu * mu;
  const float rs = rsqrtf(var + 1e-5f);
  float4 gv = ((const float4*)gamma)[t];
  float4 bv = ((const float4*)beta)[t];
  float4 o;
  o.x = (v.x - mu) * rs * gv.x + bv.x;
  o.y = (v.y - mu) * rs * gv.y + bv.y;
  o.z = (v.z - mu) * rs * gv.z + bv.z;
  o.w = (v.w - mu) * rs * gv.w + bv.w;
  if (WF32) ((float4*)(of + (size_t)row * D_MODEL))[t] = o;
  f16x4 h4 = {(_Float16)o.x, (_Float16)o.y, (_Float16)o.z, (_Float16)o.w};
  ((f16x4*)(oh + (size_t)row * D_MODEL))[t] = h4;
}

// ---------------- MFMA GEMM with global_load_lds staging ----------------
// A f16 [M][K], BT f16 [N][K]. 128x128 tile, BK=32, 4 waves, 4x4 16x16x32 MFMAs/wave.
// MODE 0: C f32 = acc + b0[col] + res          (Wo proj, MLP2)
// MODE 1: C f16 = gelu(acc + b0[col])          (MLP1)
// MODE 2: fused QKV: q*scale,k -> qk[M][256]; v -> vt[B][128][S] transposed
template <int MODE>
__global__ __launch_bounds__(256) void mfma_gemm(const _Float16* __restrict__ A,
                                                 const _Float16* __restrict__ BT,
                                                 const float* __restrict__ b0p,
                                                 const float* __restrict__ b1p,
                                                 const float* __restrict__ b2p,
                                                 const float* __restrict__ res,
                                                 void* __restrict__ Cout,
                                                 _Float16* __restrict__ vtout,
                                                 int M, int N, int K) {
  __shared__ _Float16 As[128 * 32];
  __shared__ _Float16 Bs[128 * 32];
  const int tid = threadIdx.x;
  const int lane = tid & 63, w = tid >> 6;
  const int wr = w >> 1, wc = w & 1;
  const int row0 = blockIdx.y << 7, col0 = blockIdx.x << 7;
  const int l15 = lane & 15, quad = lane >> 4;
  const f32x4 zero = {0.f, 0.f, 0.f, 0.f};
  f32x4 acc[4][4];
#pragma unroll
  for (int i = 0; i < 4; i++)
#pragma unroll
    for (int j = 0; j < 4; j++) acc[i][j] = zero;

  const int srow = lane >> 2;          // 0..15
  const int scol = (lane & 3) << 3;    // 0,8,16,24
  const _Float16* Ag = A + (size_t)(row0 + w * 32 + srow) * K + scol;
  const _Float16* Bg = BT + (size_t)(col0 + w * 32 + srow) * K + scol;

  for (int k0 = 0; k0 < K; k0 += 32) {
#pragma unroll
    for (int p = 0; p < 2; p++) {
      gload_lds16(Ag + (size_t)(p * 16) * K + k0, &As[(w * 32 + p * 16) * 32]);
      gload_lds16(Bg + (size_t)(p * 16) * K + k0, &Bs[(w * 32 + p * 16) * 32]);
    }
    __syncthreads();
    f16x8 af[4], bfr[4];
#pragma unroll
    for (int i = 0; i < 4; i++) {
      af[i]  = *(const f16x8*)&As[(wr * 64 + i * 16 + l15) * 32 + quad * 8];
      bfr[i] = *(const f16x8*)&Bs[(wc * 64 + i * 16 + l15) * 32 + quad * 8];
    }
#pragma unroll
    for (int i = 0; i < 4; i++)
#pragma unroll
      for (int j = 0; j < 4; j++)
        acc[i][j] = __builtin_amdgcn_mfma_f32_16x16x32_f16(af[i], bfr[j], acc[i][j], 0, 0, 0);
    __syncthreads();
  }

  // Epilogue. C/D layout: col = l15, row = quad*4 + r  [verified rounds 1-2]
  if (MODE == 0) {
    float* C = (float*)Cout;
#pragma unroll
    for (int j = 0; j < 4; j++) {
      const int col = col0 + wc * 64 + j * 16 + l15;
      const float bv = b0p[col];
#pragma unroll
      for (int i = 0; i < 4; i++)
#pragma unroll
        for (int r = 0; r < 4; r++) {
          const int row = row0 + wr * 64 + i * 16 + quad * 4 + r;
          C[(size_t)row * N + col] = acc[i][j][r] + bv + res[(size_t)row * N + col];
        }
    }
  } else if (MODE == 1) {
    _Float16* C = (_Float16*)Cout;
#pragma unroll
    for (int j = 0; j < 4; j++) {
      const int col = col0 + wc * 64 + j * 16 + l15;
      const float bv = b0p[col];
#pragma unroll
      for (int i = 0; i < 4; i++)
#pragma unroll
        for (int r = 0; r < 4; r++) {
          const int row = row0 + wr * 64 + i * 16 + quad * 4 + r;
          float v = acc[i][j][r] + bv;
          v = 0.5f * v * (1.0f + erff(v * 0.70710678118654752f));
          C[(size_t)row * N + col] = (_Float16)v;
        }
    }
  } else {
    _Float16* qkout = (_Float16*)Cout;
#pragma unroll
    for (int j = 0; j < 4; j++) {
      const int colbase = col0 + wc * 64 + j * 16;
      const int region = colbase >> 7;     // 0=q 1=k 2=v (uniform per j)
      if (region == 0) {
        const float bv = b0p[colbase + l15];
#pragma unroll
        for (int i = 0; i < 4; i++)
#pragma unroll
          for (int r = 0; r < 4; r++) {
            const int row = row0 + wr * 64 + i * 16 + quad * 4 + r;
            qkout[(size_t)row * 256 + colbase + l15] =
                (_Float16)((acc[i][j][r] + bv) * ATT_SCALE);
          }
      } else if (region == 1) {
        const float bv = b1p[colbase - 128 + l15];
#pragma unroll
        for (int i = 0; i < 4; i++)
#pragma unroll
          for (int r = 0; r < 4; r++) {
            const int row = row0 + wr * 64 + i * 16 + quad * 4 + r;
            qkout[(size_t)row * 256 + colbase + l15] = (_Float16)(acc[i][j][r] + bv);
          }
      } else {
        const int vd = colbase - 256 + l15;
        const float bv = b2p[vd];
#pragma unroll
        for (int i = 0; i < 4; i++) {
          const int rbase = row0 + wr * 64 + i * 16 + quad * 4;
          const int bb = rbase >> 11, s0 = rbase & 2047;
          ushort4 h;
          h.x = f16bits(acc[i][j][0] + bv);
          h.y = f16bits(acc[i][j][1] + bv);
          h.z = f16bits(acc[i][j][2] + bv);
          h.w = f16bits(acc[i][j][3] + bv);
          *(ushort4*)&vtout[((size_t)bb * 128 + vd) * SEQ + s0] = h;
        }
      }
    }
  }
}

// ---------------- MFMA flash attention ----------------
// Grid (SEQ/64, B), 256 thr = 4 waves, 16 queries/wave. 64-key tiles.
// qk: [B*S][256] f16 (q pre-scaled, k). vt: [B][128][S] f16. H: [B*S][128] f16.
__global__ __launch_bounds__(256) void flash_attn_mfma(const _Float16* __restrict__ qk,
                                                       const _Float16* __restrict__ vt,
                                                       _Float16* __restrict__ H) {
  __shared__ _Float16 Ks[2][64][136];   // keys x d, pad 8
  __shared__ _Float16 Vs[128][72];      // d x keys, pad 8
  __shared__ _Float16 Ps[4][16][72];    // per-wave P: q x keys, pad 8
  const int b = blockIdx.y, q0 = blockIdx.x * 64;
  const int tid = threadIdx.x;
  const int lane = tid & 63, w = tid >> 6;
  const int l15 = lane & 15, quad = lane >> 4;

  // Q fragments (A-layout), q pre-scaled by 1/sqrt(dk)
  f16x8 qf[4];
  {
    const _Float16* qrow = qk + ((size_t)(b * SEQ + q0 + w * 16 + l15)) * 256 + quad * 8;
#pragma unroll
    for (int ks = 0; ks < 4; ks++) qf[ks] = *(const f16x8*)(qrow + ks * 32);
  }
  const f32x4 zero = {0.f, 0.f, 0.f, 0.f};
  f32x4 O[8];
#pragma unroll
  for (int i = 0; i < 8; i++) O[i] = zero;
  float m_r[4] = {-1e30f, -1e30f, -1e30f, -1e30f};
  float l_r[4] = {0.f, 0.f, 0.f, 0.f};

  // staging: K chunk (tid>>4)+16p row, (tid&15)*8 col; V chunk (tid>>3)+32p row, (tid&7)*8 col
  const _Float16* kg0 = qk + (size_t)(b * SEQ) * 256 + 128 + (size_t)(tid >> 4) * 256 + (tid & 15) * 8;
  const _Float16* vg0 = vt + (size_t)b * 128 * SEQ + (size_t)((tid >> 3)) * SEQ + (tid & 7) * 8;
  uint4 kp[4], vp[4];

#define LOAD_TILE(kt)                                                            \
  {                                                                              \
    const _Float16* kg = kg0 + (size_t)(kt) * 64 * 256;                          \
    const _Float16* vg = vg0 + (size_t)(kt) * 64;                                \
    _Pragma("unroll") for (int p = 0; p < 4; p++) {                              \
      kp[p] = *(const uint4*)(kg + (size_t)p * 16 * 256);                        \
      vp[p] = *(const uint4*)(vg + (size_t)p * 32 * SEQ);                        \
    }                                                                            \
  }
#define STORE_K(buf)                                                             \
  _Pragma("unroll") for (int p = 0; p < 4; p++)                                  \
      *(uint4*)&Ks[buf][(tid >> 4) + 16 * p][(tid & 15) * 8] = kp[p];
#define STORE_V()                                                                \
  _Pragma("unroll") for (int p = 0; p < 4; p++)                                  \
      *(uint4*)&Vs[(tid >> 3) + 32 * p][(tid & 7) * 8] = vp[p];

  LOAD_TILE(0);
  STORE_K(0);
  STORE_V();
  __syncthreads();

  const int NT = SEQ / 64;
  for (int kt = 0; kt < NT; kt++) {
    const int cur = kt & 1;
    if (kt + 1 < NT) LOAD_TILE(kt + 1);

    // S = Q K^T  (4 key-tiles of 16)
    f32x4 s4[4];
#pragma unroll
    for (int nt = 0; nt < 4; nt++) {
      s4[nt] = zero;
#pragma unroll
      for (int ks = 0; ks < 4; ks++) {
        f16x8 kf = *(const f16x8*)&Ks[cur][nt * 16 + l15][ks * 32 + quad * 8];
        s4[nt] = __builtin_amdgcn_mfma_f32_16x16x32_f16(qf[ks], kf, s4[nt], 0, 0, 0);
      }
    }
    // online softmax; row = quad*4 + r, spread over 16 l15 lanes
    float rmax[4], alpha[4], rsum[4];
#pragma unroll
    for (int r = 0; r < 4; r++)
      rmax[r] = fmaxf(fmaxf(s4[0][r], s4[1][r]), fmaxf(s4[2][r], s4[3][r]));
#pragma unroll
    for (int o = 1; o < 16; o <<= 1)
#pragma unroll
      for (int r = 0; r < 4; r++) rmax[r] = fmaxf(rmax[r], __shfl_xor(rmax[r], o, 64));
#pragma unroll
    for (int r = 0; r < 4; r++) {
      const float nm = fmaxf(m_r[r], rmax[r]);
      alpha[r] = __expf(m_r[r] - nm);
      m_r[r] = nm;
#pragma unroll
      for (int nt = 0; nt < 4; nt++) s4[nt][r] = __expf(s4[nt][r] - nm);
      rsum[r] = s4[0][r] + s4[1][r] + s4[2][r] + s4[3][r];
    }
#pragma unroll
    for (int o = 1; o < 16; o <<= 1)
#pragma unroll
      for (int r = 0; r < 4; r++) rsum[r] += __shfl_xor(rsum[r], o, 64);
#pragma unroll
    for (int r = 0; r < 4; r++) {
      l_r[r] = l_r[r] * alpha[r] + rsum[r];
#pragma unroll
      for (int i = 0; i < 8; i++) O[i][r] *= alpha[r];
    }
    // P -> LDS (C-layout write), read back in A-layout (same wave, in-order DS)
#pragma unroll
    for (int nt = 0; nt < 4; nt++)
#pragma unroll
      for (int r = 0; r < 4; r++)
        Ps[w][quad * 4 + r][nt * 16 + l15] = (_Float16)s4[nt][r];
    f16x8 pa[2];
#pragma unroll
    for (int ks = 0; ks < 2; ks++)
      pa[ks] = *(const f16x8*)&Ps[w][l15][ks * 32 + quad * 8];
    // O += P @ V  (8 vdim-tiles of 16)
#pragma unroll
    for (int ks = 0; ks < 2; ks++)
#pragma unroll
      for (int vt8 = 0; vt8 < 8; vt8++) {
        f16x8 vf = *(const f16x8*)&Vs[vt8 * 16 + l15][ks * 32 + quad * 8];
        O[vt8] = __builtin_amdgcn_mfma_f32_16x16x32_f16(pa[ks], vf, O[vt8], 0, 0, 0);
      }

    if (kt + 1 < NT) {
      STORE_K(cur ^ 1);        // other K buffer: safe without barrier
      __syncthreads();         // all waves done reading Vs for this tile
      STORE_V();
      __syncthreads();         // next tile K+V visible
    }
  }
  // epilogue: H[q][vd] = O / l
#pragma unroll
  for (int r = 0; r < 4; r++) {
    const float inv = 1.0f / l_r[r];
    _Float16* hp = H + (size_t)(b * SEQ + q0 + w * 16 + quad * 4 + r) * D_HEAD;
#pragma unroll
    for (int vt8 = 0; vt8 < 8; vt8++)
      hp[vt8 * 16 + l15] = (_Float16)(O[vt8][r] * inv);
  }
}

// ---------------- launch ----------------
extern "C" void kernel_launch(void* const* d_in, const int* in_sizes, int n_in,
                              void* d_out, int out_size, void* d_ws, size_t ws_size,
                              hipStream_t stream) {
  const float* x     = (const float*)d_in[0];
  const float* ln1_g = (const float*)d_in[1];
  const float* ln1_b = (const float*)d_in[2];
  const float* Wq    = (const float*)d_in[3];
  const float* bq    = (const float*)d_in[4];
  const float* Wk    = (const float*)d_in[5];
  const float* bk    = (const float*)d_in[6];
  const float* Wv    = (const float*)d_in[7];
  const float* bv    = (const float*)d_in[8];
  const float* Wo    = (const float*)d_in[9];
  const float* bo    = (const float*)d_in[10];
  const float* ln2_g = (const float*)d_in[11];
  const float* ln2_b = (const float*)d_in[12];
  const float* W1    = (const float*)d_in[13];
  const float* b1    = (const float*)d_in[14];
  const float* W2    = (const float*)d_in[15];
  const float* b2    = (const float*)d_in[16];
  float* out = (float*)d_out;

  // Workspace (<=180 MiB), lifetime-overlapped:
  //  [0,8M) W1T | [8,16M) W2T | [16,16.75M) WqkvT | [16.75,17M) WoT
  //  [20,84M) xn_f32 (K1..K4) | [84,116M) xn_f16 (K1..K2)
  //  [116,124M) qk (K2..K3) | [124,128M) vt (K2..K3) | [128,132M) Hb (K3..K4)
  //  [20,148M) act f16 (K6..K7, reuses dead buffers) | [148,180M) h16 (K5..K6)
  char* ws = (char*)d_ws;
  const size_t MB = 1024 * 1024;
  _Float16* W1T   = (_Float16*)(ws);
  _Float16* W2T   = (_Float16*)(ws + 8 * MB);
  _Float16* WqkvT = (_Float16*)(ws + 16 * MB);
  _Float16* WoT   = (_Float16*)(ws + 16 * MB + 768 * 1024);
  float*    xn_f32 = (float*)(ws + 20 * MB);
  _Float16* xn_f16 = (_Float16*)(ws + 84 * MB);
  _Float16* qkb  = (_Float16*)(ws + 116 * MB);
  _Float16* vtb  = (_Float16*)(ws + 124 * MB);
  _Float16* Hb   = (_Float16*)(ws + 128 * MB);
  _Float16* act  = (_Float16*)(ws + 20 * MB);
  _Float16* h16  = (_Float16*)(ws + 148 * MB);

  // K0: weight convert+transpose (Wq/Wk/Wv into one contiguous [384][1024])
  convt_kernel<<<dim3(D_FF / 32, D_MODEL / 32), 256, 0, stream>>>(W1, W1T, D_MODEL, D_FF);
  convt_kernel<<<dim3(D_MODEL / 32, D_FF / 32), 256, 0, stream>>>(W2, W2T, D_FF, D_MODEL);
  convt_kernel<<<dim3(D_HEAD / 32, D_MODEL / 32), 256, 0, stream>>>(Wq, WqkvT, D_MODEL, D_HEAD);
  convt_kernel<<<dim3(D_HEAD / 32, D_MODEL / 32), 256, 0, stream>>>(Wk, WqkvT + 128 * 1024, D_MODEL, D_HEAD);
  convt_kernel<<<dim3(D_HEAD / 32, D_MODEL / 32), 256, 0, stream>>>(Wv, WqkvT + 256 * 1024, D_MODEL, D_HEAD);
  convt_kernel<<<dim3(D_MODEL / 32, D_HEAD / 32), 256, 0, stream>>>(Wo, WoT, D_HEAD, D_MODEL);
  // K1: LN1
  ln_kernel<true><<<dim3(M_TOT), 256, 0, stream>>>(x, ln1_g, ln1_b, xn_f32, xn_f16);
  // K2: fused QKV projection -> qk[M][256] (q scaled) + vt[B][128][S]
  mfma_gemm<2><<<dim3(3, M_TOT / 128), 256, 0, stream>>>(
      xn_f16, WqkvT, bq, bk, bv, nullptr, qkb, vtb, M_TOT, 384, D_MODEL);
  // K3: flash attention -> Hb f16
  flash_attn_mfma<<<dim3(SEQ / 64, NBATCH), 256, 0, stream>>>(qkb, vtb, Hb);
  // K4: y = xn + H @ Wo + bo -> out f32
  mfma_gemm<0><<<dim3(D_MODEL / 128, M_TOT / 128), 256, 0, stream>>>(
      Hb, WoT, bo, nullptr, nullptr, xn_f32, out, nullptr, M_TOT, D_MODEL, D_HEAD);
  // K5: LN2 -> h16
  ln_kernel<false><<<dim3(M_TOT), 256, 0, stream>>>(out, ln2_g, ln2_b, nullptr, h16);
  // K6: act = gelu(h @ W1 + b1) f16
  mfma_gemm<1><<<dim3(D_FF / 128, M_TOT / 128), 256, 0, stream>>>(
      h16, W1T, b1, nullptr, nullptr, nullptr, act, nullptr, M_TOT, D_FF, D_MODEL);
  // K7: out = y + act @ W2 + b2
  mfma_gemm<0><<<dim3(D_MODEL / 128, M_TOT / 128), 256, 0, stream>>>(
      act, W2T, b2, nullptr, nullptr, out, out, nullptr, M_TOT, D_MODEL, D_FF);

  (void)in_sizes; (void)n_in; (void)out_size; (void)ws_size;
}

// Round 4
// 802.746 us; speedup vs baseline: 11.0651x; 1.0111x over previous
//
#include <hip/hip_runtime.h>
#include <math.h>

// Problem constants (B=8, S=2048, D=1024, DK=DV=128, FF=4096)
#define M_TOT   16384
#define D_MODEL 1024
#define D_HEAD  128
#define SEQ     2048
#define NBATCH  8
#define D_FF    4096

typedef _Float16 f16x8 __attribute__((ext_vector_type(8)));
typedef _Float16 f16x4 __attribute__((ext_vector_type(4)));
typedef float    f32x4 __attribute__((ext_vector_type(4)));

#define ATT_SCALE 0.08838834764831845f  // 1/sqrt(128)

__device__ __forceinline__ void gload_lds16(const _Float16* g, _Float16* l) {
  __builtin_amdgcn_global_load_lds(
      (const __attribute__((address_space(1))) unsigned int*)g,
      (__attribute__((address_space(3))) unsigned int*)l, 16, 0, 0);
}
__device__ __forceinline__ unsigned short f16bits(float v) {
  union { _Float16 f; unsigned short u; } cv; cv.f = (_Float16)v; return cv.u;
}
// tanh-form GELU: 0.5x(1+tanh(0.79788456(x+0.044715x^3))); overflow-safe, ~8 VALU ops
__device__ __forceinline__ float gelu_f(float x) {
  const float t = 0.7978845608028654f * x * (1.0f + 0.044715f * x * x);
  const float e = __expf(2.0f * t);
  const float th = 1.0f - 2.0f / (e + 1.0f);
  return 0.5f * x * (1.0f + th);
}

// ---------------- weight convert + transpose: out[n][k] = f16(in[k][n]) ----------------
__global__ __launch_bounds__(256) void convt_kernel(const float* __restrict__ in,
                                                    _Float16* __restrict__ out,
                                                    int K, int N) {
  __shared__ float t[32][33];
  const int n0 = blockIdx.x * 32, k0 = blockIdx.y * 32;
  const int tx = threadIdx.x & 31, ty = threadIdx.x >> 5;   // 32 x 8
#pragma unroll
  for (int r = 0; r < 4; r++)
    t[ty + 8 * r][tx] = in[(size_t)(k0 + ty + 8 * r) * N + n0 + tx];
  __syncthreads();
#pragma unroll
  for (int r = 0; r < 4; r++)
    out[(size_t)(n0 + ty + 8 * r) * K + k0 + tx] = (_Float16)t[tx][ty + 8 * r];
}

// ---------------- LayerNorm: one block (256 thr) per row of 1024 ----------------
template <bool WF32>
__global__ __launch_bounds__(256) void ln_kernel(const float* __restrict__ in,
                                                 const float* __restrict__ gamma,
                                                 const float* __restrict__ beta,
                                                 float* __restrict__ of,
                                                 _Float16* __restrict__ oh) {
  __shared__ float shs[4], shq[4];
  const int row = blockIdx.x;
  const int t = threadIdx.x;
  float4 v = ((const float4*)(in + (size_t)row * D_MODEL))[t];
  float s = v.x + v.y + v.z + v.w;
  float q = v.x * v.x + v.y * v.y + v.z * v.z + v.w * v.w;
#pragma unroll
  for (int o = 32; o > 0; o >>= 1) {
    s += __shfl_down(s, o, 64);
    q += __shfl_down(q, o, 64);
  }
  const int lane = t & 63, w = t >> 6;
  if (lane == 0) { shs[w] = s; shq[w] = q; }
  __syncthreads();
  if (t == 0) {
    shs[0] = shs[0] + shs[1] + shs[2] + shs[3];
    shq[0] = shq[0] + shq[1] + shq[2] + shq[3];
  }
  __syncthreads();
  const float mu = shs[0] * (1.0f / D_MODEL);
  const float var = shq[0] * (1.0f / D_MODEL) - mu * mu;
  const float rs = rsqrtf(var + 1e-5f);
  float4 gv = ((const float4*)gamma)[t];
  float4 bv = ((const float4*)beta)[t];
  float4 o;
  o.x = (v.x - mu) * rs * gv.x + bv.x;
  o.y = (v.y - mu) * rs * gv.y + bv.y;
  o.z = (v.z - mu) * rs * gv.z + bv.z;
  o.w = (v.w - mu) * rs * gv.w + bv.w;
  if (WF32) ((float4*)(of + (size_t)row * D_MODEL))[t] = o;
  f16x4 h4 = {(_Float16)o.x, (_Float16)o.y, (_Float16)o.z, (_Float16)o.w};
  ((f16x4*)(oh + (size_t)row * D_MODEL))[t] = h4;
}

// ---------------- MFMA GEMM with global_load_lds staging ----------------
// A f16 [M][K], BT f16 [N][K]. 128x128 tile, BK=32, 4 waves, 4x4 16x16x32 MFMAs/wave.
// MODE 0: C f32 = acc + b0[col] + res          (Wo proj, MLP2)
// MODE 1: C f16 = gelu(acc + b0[col])          (MLP1)
// MODE 2: fused QKV: bx=0 q*scale, bx=1 k -> qk[M][256]; bx=2 v -> vt[B][128][S]
template <int MODE>
__global__ __launch_bounds__(256) void mfma_gemm(const _Float16* __restrict__ A,
                                                 const _Float16* __restrict__ BT,
                                                 const float* __restrict__ b0p,
                                                 const float* __restrict__ b1p,
                                                 const float* __restrict__ b2p,
                                                 const float* __restrict__ res,
                                                 void* __restrict__ Cout,
                                                 _Float16* __restrict__ vtout,
                                                 int M, int N, int K) {
  __shared__ _Float16 SMEM[2 * 128 * 32];   // As | Bs ; aliased as Ts in MODE2-V epilogue
  _Float16* As = SMEM;
  _Float16* Bs = SMEM + 128 * 32;
  const int tid = threadIdx.x;
  const int lane = tid & 63, w = tid >> 6;
  const int wr = w >> 1, wc = w & 1;
  const int row0 = blockIdx.y << 7, col0 = blockIdx.x << 7;
  const int l15 = lane & 15, quad = lane >> 4;
  const f32x4 zero = {0.f, 0.f, 0.f, 0.f};
  f32x4 acc[4][4];
#pragma unroll
  for (int i = 0; i < 4; i++)
#pragma unroll
    for (int j = 0; j < 4; j++) acc[i][j] = zero;

  const int srow = lane >> 2;          // 0..15
  const int scol = (lane & 3) << 3;    // 0,8,16,24
  const _Float16* Ag = A + (size_t)(row0 + w * 32 + srow) * K + scol;
  const _Float16* Bg = BT + (size_t)(col0 + w * 32 + srow) * K + scol;

  for (int k0 = 0; k0 < K; k0 += 32) {
#pragma unroll
    for (int p = 0; p < 2; p++) {
      gload_lds16(Ag + (size_t)(p * 16) * K + k0, &As[(w * 32 + p * 16) * 32]);
      gload_lds16(Bg + (size_t)(p * 16) * K + k0, &Bs[(w * 32 + p * 16) * 32]);
    }
    __syncthreads();
    f16x8 af[4], bfr[4];
#pragma unroll
    for (int i = 0; i < 4; i++) {
      af[i]  = *(const f16x8*)&As[(wr * 64 + i * 16 + l15) * 32 + quad * 8];
      bfr[i] = *(const f16x8*)&Bs[(wc * 64 + i * 16 + l15) * 32 + quad * 8];
    }
#pragma unroll
    for (int i = 0; i < 4; i++)
#pragma unroll
      for (int j = 0; j < 4; j++)
        acc[i][j] = __builtin_amdgcn_mfma_f32_16x16x32_f16(af[i], bfr[j], acc[i][j], 0, 0, 0);
    __syncthreads();
  }

  // Epilogue. C/D layout: col = l15, row = quad*4 + r  [verified rounds 1-3]
  // j-INNERMOST so 4 stores complete a full 128B line per (row,quad) back-to-back.
  if (MODE == 0) {
    float* C = (float*)Cout;
    float bv4[4];
#pragma unroll
    for (int j = 0; j < 4; j++) bv4[j] = b0p[col0 + wc * 64 + j * 16 + l15];
#pragma unroll
    for (int i = 0; i < 4; i++)
#pragma unroll
      for (int r = 0; r < 4; r++) {
        const int row = row0 + wr * 64 + i * 16 + quad * 4 + r;
        const size_t base = (size_t)row * N + col0 + wc * 64 + l15;
        const float* rp = res + base;
        float* cp = C + base;
#pragma unroll
        for (int j = 0; j < 4; j++)
          cp[j * 16] = acc[i][j][r] + bv4[j] + rp[j * 16];
      }
  } else if (MODE == 1) {
    _Float16* C = (_Float16*)Cout;
    float bv4[4];
#pragma unroll
    for (int j = 0; j < 4; j++) bv4[j] = b0p[col0 + wc * 64 + j * 16 + l15];
#pragma unroll
    for (int i = 0; i < 4; i++)
#pragma unroll
      for (int r = 0; r < 4; r++) {
        const int row = row0 + wr * 64 + i * 16 + quad * 4 + r;
        _Float16* cp = C + (size_t)row * N + col0 + wc * 64 + l15;
#pragma unroll
        for (int j = 0; j < 4; j++)
          cp[j * 16] = (_Float16)gelu_f(acc[i][j][r] + bv4[j]);
      }
  } else {
    _Float16* qkout = (_Float16*)Cout;
    const int bx = blockIdx.x;
    if (bx < 2) {
      // q (scaled) or k -> qk[M][256]
      const float* bp = (bx == 0) ? b0p : b1p;
      const float sc = (bx == 0) ? ATT_SCALE : 1.0f;
      const int cofs = bx * 128 + wc * 64 + l15;
      float bv4[4];
#pragma unroll
      for (int j = 0; j < 4; j++) bv4[j] = bp[wc * 64 + j * 16 + l15];
#pragma unroll
      for (int i = 0; i < 4; i++)
#pragma unroll
        for (int r = 0; r < 4; r++) {
          const int row = row0 + wr * 64 + i * 16 + quad * 4 + r;
          _Float16* cp = qkout + (size_t)row * 256 + cofs;
#pragma unroll
          for (int j = 0; j < 4; j++)
            cp[j * 16] = (_Float16)((acc[i][j][r] + bv4[j]) * sc);
        }
    } else {
      // v -> vt[B][128][S], via LDS transpose (Ts[vd][40] f16, aliases SMEM)
      _Float16* Ts = SMEM;
      float bv4[4];
#pragma unroll
      for (int j = 0; j < 4; j++) bv4[j] = b2p[wc * 64 + j * 16 + l15];
      const int bb = row0 >> 11, s0 = row0 & 2047;
#pragma unroll
      for (int c = 0; c < 4; c++) {        // s-chunk [c*32, c*32+32)
        __syncthreads();
        if (wr == (c >> 1)) {
#pragma unroll
          for (int ii = 0; ii < 2; ii++) {
            const int i = (c & 1) * 2 + ii;
#pragma unroll
            for (int j = 0; j < 4; j++) {
              const int vd = wc * 64 + j * 16 + l15;
              const int slocal = ii * 16 + quad * 4;
              ushort4 h;
              h.x = f16bits(acc[i][j][0] + bv4[j]);
              h.y = f16bits(acc[i][j][1] + bv4[j]);
              h.z = f16bits(acc[i][j][2] + bv4[j]);
              h.w = f16bits(acc[i][j][3] + bv4[j]);
              *(ushort4*)&Ts[vd * 40 + slocal] = h;
            }
          }
        }
        __syncthreads();
#pragma unroll
        for (int p = 0; p < 2; p++) {
          const int idx = tid + p * 256;       // 0..511
          const int vd = idx >> 2, s8 = (idx & 3) * 8;
          uint4 d = *(const uint4*)&Ts[vd * 40 + s8];
          *(uint4*)&vtout[((size_t)bb * 128 + vd) * SEQ + s0 + c * 32 + s8] = d;
        }
      }
    }
  }
}

// ---------------- MFMA flash attention ----------------
// Grid (SEQ/64, B), 256 thr = 4 waves, 16 queries/wave. 64-key tiles.
// qk: [B*S][256] f16 (q pre-scaled, k). vt: [B][128][S] f16. H: [B*S][128] f16.
__global__ __launch_bounds__(256) void flash_attn_mfma(const _Float16* __restrict__ qk,
                                                       const _Float16* __restrict__ vt,
                                                       _Float16* __restrict__ H) {
  __shared__ _Float16 Ks[2][64][136];   // keys x d, pad 8
  __shared__ _Float16 Vs[128][72];      // d x keys, pad 8
  __shared__ _Float16 Ps[4][16][72];    // per-wave P: q x keys, pad 8
  const int b = blockIdx.y, q0 = blockIdx.x * 64;
  const int tid = threadIdx.x;
  const int lane = tid & 63, w = tid >> 6;
  const int l15 = lane & 15, quad = lane >> 4;

  // Q fragments (A-layout), q pre-scaled by 1/sqrt(dk)
  f16x8 qf[4];
  {
    const _Float16* qrow = qk + ((size_t)(b * SEQ + q0 + w * 16 + l15)) * 256 + quad * 8;
#pragma unroll
    for (int ks = 0; ks < 4; ks++) qf[ks] = *(const f16x8*)(qrow + ks * 32);
  }
  const f32x4 zero = {0.f, 0.f, 0.f, 0.f};
  f32x4 O[8];
#pragma unroll
  for (int i = 0; i < 8; i++) O[i] = zero;
  float m_r[4] = {-1e30f, -1e30f, -1e30f, -1e30f};
  float l_r[4] = {0.f, 0.f, 0.f, 0.f};

  const _Float16* kg0 = qk + (size_t)(b * SEQ) * 256 + 128 + (size_t)(tid >> 4) * 256 + (tid & 15) * 8;
  const _Float16* vg0 = vt + (size_t)b * 128 * SEQ + (size_t)((tid >> 3)) * SEQ + (tid & 7) * 8;
  uint4 kp[4], vp[4];

#define LOAD_TILE(kt)                                                            \
  {                                                                              \
    const _Float16* kg = kg0 + (size_t)(kt) * 64 * 256;                          \
    const _Float16* vg = vg0 + (size_t)(kt) * 64;                                \
    _Pragma("unroll") for (int p = 0; p < 4; p++) {                              \
      kp[p] = *(const uint4*)(kg + (size_t)p * 16 * 256);                        \
      vp[p] = *(const uint4*)(vg + (size_t)p * 32 * SEQ);                        \
    }                                                                            \
  }
#define STORE_K(buf)                                                             \
  _Pragma("unroll") for (int p = 0; p < 4; p++)                                  \
      *(uint4*)&Ks[buf][(tid >> 4) + 16 * p][(tid & 15) * 8] = kp[p];
#define STORE_V()                                                                \
  _Pragma("unroll") for (int p = 0; p < 4; p++)                                  \
      *(uint4*)&Vs[(tid >> 3) + 32 * p][(tid & 7) * 8] = vp[p];

  LOAD_TILE(0);
  STORE_K(0);
  STORE_V();
  __syncthreads();

  const int NT = SEQ / 64;
  for (int kt = 0; kt < NT; kt++) {
    const int cur = kt & 1;
    if (kt + 1 < NT) LOAD_TILE(kt + 1);

    // S = Q K^T  (4 key-tiles of 16)
    f32x4 s4[4];
#pragma unroll
    for (int nt = 0; nt < 4; nt++) {
      s4[nt] = zero;
#pragma unroll
      for (int ks = 0; ks < 4; ks++) {
        f16x8 kf = *(const f16x8*)&Ks[cur][nt * 16 + l15][ks * 32 + quad * 8];
        s4[nt] = __builtin_amdgcn_mfma_f32_16x16x32_f16(qf[ks], kf, s4[nt], 0, 0, 0);
      }
    }
    // online softmax; row = quad*4 + r, spread over 16 l15 lanes
    float rmax[4], alpha[4], rsum[4];
#pragma unroll
    for (int r = 0; r < 4; r++)
      rmax[r] = fmaxf(fmaxf(s4[0][r], s4[1][r]), fmaxf(s4[2][r], s4[3][r]));
#pragma unroll
    for (int o = 1; o < 16; o <<= 1)
#pragma unroll
      for (int r = 0; r < 4; r++) rmax[r] = fmaxf(rmax[r], __shfl_xor(rmax[r], o, 64));
#pragma unroll
    for (int r = 0; r < 4; r++) {
      const float nm = fmaxf(m_r[r], rmax[r]);
      alpha[r] = __expf(m_r[r] - nm);
      m_r[r] = nm;
#pragma unroll
      for (int nt = 0; nt < 4; nt++) s4[nt][r] = __expf(s4[nt][r] - nm);
      rsum[r] = s4[0][r] + s4[1][r] + s4[2][r] + s4[3][r];
    }
#pragma unroll
    for (int o = 1; o < 16; o <<= 1)
#pragma unroll
      for (int r = 0; r < 4; r++) rsum[r] += __shfl_xor(rsum[r], o, 64);
#pragma unroll
    for (int r = 0; r < 4; r++) {
      l_r[r] = l_r[r] * alpha[r] + rsum[r];
#pragma unroll
      for (int i = 0; i < 8; i++) O[i][r] *= alpha[r];
    }
    // P -> LDS (C-layout write), read back in A-layout (same wave, in-order DS)
#pragma unroll
    for (int nt = 0; nt < 4; nt++)
#pragma unroll
      for (int r = 0; r < 4; r++)
        Ps[w][quad * 4 + r][nt * 16 + l15] = (_Float16)s4[nt][r];
    f16x8 pa[2];
#pragma unroll
    for (int ks = 0; ks < 2; ks++)
      pa[ks] = *(const f16x8*)&Ps[w][l15][ks * 32 + quad * 8];
    // O += P @ V  (8 vdim-tiles of 16)
#pragma unroll
    for (int ks = 0; ks < 2; ks++)
#pragma unroll
      for (int vt8 = 0; vt8 < 8; vt8++) {
        f16x8 vf = *(const f16x8*)&Vs[vt8 * 16 + l15][ks * 32 + quad * 8];
        O[vt8] = __builtin_amdgcn_mfma_f32_16x16x32_f16(pa[ks], vf, O[vt8], 0, 0, 0);
      }

    if (kt + 1 < NT) {
      STORE_K(cur ^ 1);        // other K buffer: safe without barrier
      __syncthreads();         // all waves done reading Vs for this tile
      STORE_V();
      __syncthreads();         // next tile K+V visible
    }
  }
  // epilogue: H[q][vd] = O / l
#pragma unroll
  for (int r = 0; r < 4; r++) {
    const float inv = 1.0f / l_r[r];
    _Float16* hp = H + (size_t)(b * SEQ + q0 + w * 16 + quad * 4 + r) * D_HEAD;
#pragma unroll
    for (int vt8 = 0; vt8 < 8; vt8++)
      hp[vt8 * 16 + l15] = (_Float16)(O[vt8][r] * inv);
  }
}

// ---------------- launch ----------------
extern "C" void kernel_launch(void* const* d_in, const int* in_sizes, int n_in,
                              void* d_out, int out_size, void* d_ws, size_t ws_size,
                              hipStream_t stream) {
  const float* x     = (const float*)d_in[0];
  const float* ln1_g = (const float*)d_in[1];
  const float* ln1_b = (const float*)d_in[2];
  const float* Wq    = (const float*)d_in[3];
  const float* bq    = (const float*)d_in[4];
  const float* Wk    = (const float*)d_in[5];
  const float* bk    = (const float*)d_in[6];
  const float* Wv    = (const float*)d_in[7];
  const float* bv    = (const float*)d_in[8];
  const float* Wo    = (const float*)d_in[9];
  const float* bo    = (const float*)d_in[10];
  const float* ln2_g = (const float*)d_in[11];
  const float* ln2_b = (const float*)d_in[12];
  const float* W1    = (const float*)d_in[13];
  const float* b1    = (const float*)d_in[14];
  const float* W2    = (const float*)d_in[15];
  const float* b2    = (const float*)d_in[16];
  float* out = (float*)d_out;

  // Workspace (<=180 MiB), lifetime-overlapped:
  //  [0,8M) W1T | [8,16M) W2T | [16,16.75M) WqkvT | [16.75,17M) WoT
  //  [20,84M) xn_f32 (K1..K4) | [84,116M) xn_f16 (K1..K2)
  //  [116,124M) qk (K2..K3) | [124,128M) vt (K2..K3) | [128,132M) Hb (K3..K4)
  //  [20,148M) act f16 (K6..K7, reuses dead buffers) | [148,180M) h16 (K5..K6)
  char* ws = (char*)d_ws;
  const size_t MB = 1024 * 1024;
  _Float16* W1T   = (_Float16*)(ws);
  _Float16* W2T   = (_Float16*)(ws + 8 * MB);
  _Float16* WqkvT = (_Float16*)(ws + 16 * MB);
  _Float16* WoT   = (_Float16*)(ws + 16 * MB + 768 * 1024);
  float*    xn_f32 = (float*)(ws + 20 * MB);
  _Float16* xn_f16 = (_Float16*)(ws + 84 * MB);
  _Float16* qkb  = (_Float16*)(ws + 116 * MB);
  _Float16* vtb  = (_Float16*)(ws + 124 * MB);
  _Float16* Hb   = (_Float16*)(ws + 128 * MB);
  _Float16* act  = (_Float16*)(ws + 20 * MB);
  _Float16* h16  = (_Float16*)(ws + 148 * MB);

  // K0: weight convert+transpose (Wq/Wk/Wv into one contiguous [384][1024])
  convt_kernel<<<dim3(D_FF / 32, D_MODEL / 32), 256, 0, stream>>>(W1, W1T, D_MODEL, D_FF);
  convt_kernel<<<dim3(D_MODEL / 32, D_FF / 32), 256, 0, stream>>>(W2, W2T, D_FF, D_MODEL);
  convt_kernel<<<dim3(D_HEAD / 32, D_MODEL / 32), 256, 0, stream>>>(Wq, WqkvT, D_MODEL, D_HEAD);
  convt_kernel<<<dim3(D_HEAD / 32, D_MODEL / 32), 256, 0, stream>>>(Wk, WqkvT + 128 * 1024, D_MODEL, D_HEAD);
  convt_kernel<<<dim3(D_HEAD / 32, D_MODEL / 32), 256, 0, stream>>>(Wv, WqkvT + 256 * 1024, D_MODEL, D_HEAD);
  convt_kernel<<<dim3(D_MODEL / 32, D_HEAD / 32), 256, 0, stream>>>(Wo, WoT, D_HEAD, D_MODEL);
  // K1: LN1
  ln_kernel<true><<<dim3(M_TOT), 256, 0, stream>>>(x, ln1_g, ln1_b, xn_f32, xn_f16);
  // K2: fused QKV projection -> qk[M][256] (q scaled) + vt[B][128][S]
  mfma_gemm<2><<<dim3(3, M_TOT / 128), 256, 0, stream>>>(
      xn_f16, WqkvT, bq, bk, bv, nullptr, qkb, vtb, M_TOT, 384, D_MODEL);
  // K3: flash attention -> Hb f16
  flash_attn_mfma<<<dim3(SEQ / 64, NBATCH), 256, 0, stream>>>(qkb, vtb, Hb);
  // K4: y = xn + H @ Wo + bo -> out f32
  mfma_gemm<0><<<dim3(D_MODEL / 128, M_TOT / 128), 256, 0, stream>>>(
      Hb, WoT, bo, nullptr, nullptr, xn_f32, out, nullptr, M_TOT, D_MODEL, D_HEAD);
  // K5: LN2 -> h16
  ln_kernel<false><<<dim3(M_TOT), 256, 0, stream>>>(out, ln2_g, ln2_b, nullptr, h16);
  // K6: act = gelu(h @ W1 + b1) f16
  mfma_gemm<1><<<dim3(D_FF / 128, M_TOT / 128), 256, 0, stream>>>(
      h16, W1T, b1, nullptr, nullptr, nullptr, act, nullptr, M_TOT, D_FF, D_MODEL);
  // K7: out = y + act @ W2 + b2
  mfma_gemm<0><<<dim3(D_MODEL / 128, M_TOT / 128), 256, 0, stream>>>(
      act, W2T, b2, nullptr, nullptr, out, out, nullptr, M_TOT, D_MODEL, D_FF);

  (void)in_sizes; (void)n_in; (void)out_size; (void)ws_size;
}